// Round 5
// baseline (511.195 us; speedup 1.0000x reference)
//
#include <hip/hip_runtime.h>
#include <hip/hip_bf16.h>

typedef __bf16 bf16;
typedef __bf16 bf16x4v __attribute__((ext_vector_type(4)));
typedef __bf16 bf16x8 __attribute__((ext_vector_type(8)));
typedef float  f32x4  __attribute__((ext_vector_type(4)));
typedef float  f32x8  __attribute__((ext_vector_type(8)));

#define MFMA16(A,B,C) __builtin_amdgcn_mfma_f32_16x16x32_bf16((A),(B),(C),0,0,0)

constexpr int   N_TOK = 49;
constexpr int   DIM_C = 256;
constexpr float SCALE = 0.17677669529663687f;   // 32^-0.5

// LDS: one region [49][256] bf16, XOR-swizzled (elem col ^= (row&7)<<3).
// Holds x-tile during stages 0-1, then ao during stages 2-3. 25,088 B.
constexpr int SMEM_ELEMS = N_TOK * 256;

// ws layout (bytes)
constexpr size_t CB_BYTES    = 64ull * 8 * 64 * 64 * 4;   // 8 MB
constexpr int    QKVW_ELEMS  = 768 * 256;
constexpr int    PROJW_ELEMS = 256 * 256;

__global__ __launch_bounds__(256) void build_cb_kernel(
    const float* __restrict__ bias_table, const float* __restrict__ mask,
    const int* __restrict__ rel_index, float* __restrict__ cb) {
  int idx = blockIdx.x * 256 + threadIdx.x;          // [64 w][8 h][64 m][64 j]
  int j = idx & 63, m = (idx >> 6) & 63, h = (idx >> 12) & 7, w = idx >> 15;
  float v = 0.f;
  if (j < N_TOK && m < N_TOK)
    v = bias_table[rel_index[m * 49 + j] * 8 + h] + mask[(w * 49 + m) * 49 + j];
  cb[idx] = v;
}

__global__ __launch_bounds__(256) void cvt_w_kernel(
    const float* __restrict__ qkv_w, const float* __restrict__ proj_w,
    bf16* __restrict__ qkv_wb, bf16* __restrict__ proj_wb) {
  int i = blockIdx.x * 256 + threadIdx.x;
  if (i < QKVW_ELEMS) qkv_wb[i] = (bf16)qkv_w[i];
  else                proj_wb[i - QKVW_ELEMS] = (bf16)proj_w[i - QKVW_ELEMS];
}

// D-frag (16x16 tiles T0,T1 stacked along p) -> A/B-frag over k=p (32 wide).
// Target reg u of lane (l15,lgp): p = lgp*8+u, held in tile (lgp>>1),
// reg u&3, source lane l15 + 16*(2*(lgp&1) + (u>>2)).
__device__ __forceinline__ bf16x8 repack8(f32x4 Ta, f32x4 Tb, int l15, int lgp) {
  const int s0 = l15 + ((lgp & 1) << 5);
  const bool hi = (lgp & 2) != 0;
  bf16x8 F;
#pragma unroll
  for (int r = 0; r < 4; ++r) {
    float a0 = __shfl(Ta[r], s0);
    float b0 = __shfl(Tb[r], s0);
    F[r] = (bf16)(hi ? b0 : a0);
    float a1 = __shfl(Ta[r], s0 + 16);
    float b1 = __shfl(Tb[r], s0 + 16);
    F[r + 4] = (bf16)(hi ? b1 : a1);
  }
  return F;
}

__device__ __forceinline__ bf16x8 tile_read(const bf16* sm, int mt, int l15, int kk) {
  int m = mt * 16 + l15;
  int mc = m < N_TOK ? m : 48;          // clamp pad rows to finite data
  return *reinterpret_cast<const bf16x8*>(&sm[mc * 256 + (kk ^ ((mc & 7) << 3))]);
}

__global__ __launch_bounds__(512, 4) void win_attn_kernel(
    const float* __restrict__ x, const bf16* __restrict__ qkv_wb,
    const float* __restrict__ qkv_b, const bf16* __restrict__ proj_wb,
    const float* __restrict__ proj_b, const float* __restrict__ cb,
    float* __restrict__ out) {
  __shared__ bf16 smem[SMEM_ELEMS];

  const int beta  = blockIdx.x;
  const int w_idx = beta >> 6;          // 64 consecutive blocks share one mask slice
  const int img   = beta & 63;
  const int b     = img * 64 + w_idx;
  const int tid   = threadIdx.x;
  const int wv    = tid >> 6;           // wave id == head id
  const int l     = tid & 63;
  const int l15   = l & 15, lgp = l >> 4;
  const int h     = wv;

  const f32x4 fzero = {0.f, 0.f, 0.f, 0.f};

  // ---------------- stage 0: x tile f32 -> LDS bf16 (swizzled) -------------
  const float* xg = x + (size_t)b * (N_TOK * DIM_C);
  for (int c = tid; c < (N_TOK * DIM_C / 8); c += 512) {
    int m = c >> 5, k0 = (c & 31) * 8;
    f32x8 f = *reinterpret_cast<const f32x8*>(xg + m * 256 + k0);
    bf16x8 v;
#pragma unroll
    for (int e = 0; e < 8; ++e) v[e] = (bf16)f[e];
    *reinterpret_cast<bf16x8*>(&smem[m * 256 + (k0 ^ ((m & 7) << 3))]) = v;
  }
  __syncthreads();

  // ---------------- stage 1 pass A: this head's Q,K (swapped: D[c,m]) ------
  bf16x8 Qf[4], Kf[4];     // B-frags per m-tile / A-frags per j-tile
  {
    f32x4 dq[2][4], dk[2][4];
#pragma unroll
    for (int i = 0; i < 2; ++i)
      for (int mt = 0; mt < 4; ++mt) { dq[i][mt] = fzero; dk[i][mt] = fzero; }
#pragma unroll 2
    for (int k0 = 0; k0 < 8; ++k0) {
      const int kk = k0 * 32 + lgp * 8;
      bf16x8 X[4];
#pragma unroll
      for (int mt = 0; mt < 4; ++mt) X[mt] = tile_read(smem, mt, l15, kk);
#pragma unroll
      for (int i = 0; i < 2; ++i) {
        int cq = (2 * h + i) * 16 + l15;
        bf16x8 Aq = *reinterpret_cast<const bf16x8*>(qkv_wb + cq * DIM_C + kk);
#pragma unroll
        for (int mt = 0; mt < 4; ++mt) dq[i][mt] = MFMA16(Aq, X[mt], dq[i][mt]);
        int ck = (16 + 2 * h + i) * 16 + l15;
        bf16x8 Ak = *reinterpret_cast<const bf16x8*>(qkv_wb + ck * DIM_C + kk);
#pragma unroll
        for (int mt = 0; mt < 4; ++mt) dk[i][mt] = MFMA16(Ak, X[mt], dk[i][mt]);
      }
    }
#pragma unroll
    for (int i = 0; i < 2; ++i) {
      f32x4 qb = *reinterpret_cast<const f32x4*>(qkv_b + (2 * h + i) * 16 + lgp * 4);
      f32x4 kb = *reinterpret_cast<const f32x4*>(qkv_b + 256 + (2 * h + i) * 16 + lgp * 4);
#pragma unroll
      for (int mt = 0; mt < 4; ++mt)
#pragma unroll
        for (int r = 0; r < 4; ++r) {
          dq[i][mt][r] = (dq[i][mt][r] + qb[r]) * SCALE;
          dk[i][mt][r] += kb[r];
        }
    }
#pragma unroll
    for (int mt = 0; mt < 4; ++mt) Qf[mt] = repack8(dq[0][mt], dq[1][mt], l15, lgp);
#pragma unroll
    for (int jt = 0; jt < 4; ++jt) Kf[jt] = repack8(dk[0][jt], dk[1][jt], l15, lgp);
  }

  // ---------------- stage 1 pass B: this head's V (unswapped: D[m,dd]) -----
  bf16x8 Vf[2][2];         // A-frags [dt][ks]
  {
    f32x4 dv[2][4];
#pragma unroll
    for (int i = 0; i < 2; ++i)
      for (int mt = 0; mt < 4; ++mt) dv[i][mt] = fzero;
#pragma unroll 2
    for (int k0 = 0; k0 < 8; ++k0) {
      const int kk = k0 * 32 + lgp * 8;
      bf16x8 X[4];
#pragma unroll
      for (int mt = 0; mt < 4; ++mt) X[mt] = tile_read(smem, mt, l15, kk);
#pragma unroll
      for (int i = 0; i < 2; ++i) {
        int cv = (32 + 2 * h + i) * 16 + l15;
        bf16x8 Bw = *reinterpret_cast<const bf16x8*>(qkv_wb + cv * DIM_C + kk);
#pragma unroll
        for (int mt = 0; mt < 4; ++mt) dv[i][mt] = MFMA16(X[mt], Bw, dv[i][mt]);
      }
    }
    __syncthreads();   // ALL x reads done (both passes); region reusable for ao
#pragma unroll
    for (int i = 0; i < 2; ++i) {
      float vb = qkv_b[512 + (32 + 2 * h + i) * 16 + l15 - 512];   // = qkv_b[cv]
#pragma unroll
      for (int mt = 0; mt < 4; ++mt)
#pragma unroll
        for (int r = 0; r < 4; ++r) dv[i][mt][r] += vb;
#pragma unroll
      for (int ks = 0; ks < 2; ++ks)
        Vf[i][ks] = repack8(dv[i][ks * 2], dv[i][ks * 2 + 1], l15, lgp);
    }
  }

  // ---------------- stage 2: S^T, softmax (register-local), PV -------------
  const float* cbp = cb + ((size_t)(w_idx * 8 + h)) * 4096;
#pragma unroll
  for (int mt = 0; mt < 4; ++mt) {
    int mrow = mt * 16 + l15;
    f32x4 cb4[4];
#pragma unroll
    for (int jt = 0; jt < 4; ++jt)
      cb4[jt] = *reinterpret_cast<const f32x4*>(cbp + mrow * 64 + jt * 16 + lgp * 4);
    f32x4 e4[4];
#pragma unroll
    for (int jt = 0; jt < 4; ++jt) e4[jt] = MFMA16(Kf[jt], Qf[mt], fzero);
#pragma unroll
    for (int jt = 0; jt < 4; ++jt)
#pragma unroll
      for (int r = 0; r < 4; ++r) {
        float v = e4[jt][r] + cb4[jt][r];
        if (jt == 3) {                      // j = 48 + lgp*4 + r : keep only j=48
          if (r != 0 || lgp != 0) v = -3.0e38f;
        }
        e4[jt][r] = v;
      }
    float mx = e4[0][0];
#pragma unroll
    for (int jt = 0; jt < 4; ++jt)
#pragma unroll
      for (int r = 0; r < 4; ++r) mx = fmaxf(mx, e4[jt][r]);
    mx = fmaxf(mx, __shfl_xor(mx, 16));
    mx = fmaxf(mx, __shfl_xor(mx, 32));
    float sum = 0.f;
#pragma unroll
    for (int jt = 0; jt < 4; ++jt)
#pragma unroll
      for (int r = 0; r < 4; ++r) {
        float ex = __expf(e4[jt][r] - mx);
        e4[jt][r] = ex;
        sum += ex;
      }
    sum += __shfl_xor(sum, 16);
    sum += __shfl_xor(sum, 32);
    float rinv = 1.0f / sum;

    bf16x8 Pf0 = repack8(e4[0], e4[1], l15, lgp);   // P^T frags (j = k-dim)
    bf16x8 Pf1 = repack8(e4[2], e4[3], l15, lgp);
    f32x4 pv0 = MFMA16(Vf[0][0], Pf0, fzero);
    pv0 = MFMA16(Vf[0][1], Pf1, pv0);
    f32x4 pv1 = MFMA16(Vf[1][0], Pf0, fzero);
    pv1 = MFMA16(Vf[1][1], Pf1, pv1);

    if (mrow < N_TOK) {                    // ao[m][32h + dt*16 + lgp*4 + r]
      bf16x4v w0, w1;
#pragma unroll
      for (int r = 0; r < 4; ++r) {
        w0[r] = (bf16)(pv0[r] * rinv);
        w1[r] = (bf16)(pv1[r] * rinv);
      }
      int sw = (mrow & 7) << 3;
      int c0 = 32 * h + lgp * 4;
      *reinterpret_cast<bf16x4v*>(&smem[mrow * 256 + (c0 ^ sw)]) = w0;
      *reinterpret_cast<bf16x4v*>(&smem[mrow * 256 + ((c0 + 16) ^ sw)]) = w1;
    }
  }
  __syncthreads();

  // ---------------- stage 3: out^T = proj_w . ao^T (swapped) ---------------
  f32x4 acc2[2][4];
#pragma unroll
  for (int ci = 0; ci < 2; ++ci)
    for (int mt = 0; mt < 4; ++mt) acc2[ci][mt] = fzero;
#pragma unroll 2
  for (int k0 = 0; k0 < 8; ++k0) {
    const int kk = k0 * 32 + lgp * 8;
    bf16x8 Bao[4];
#pragma unroll
    for (int mt = 0; mt < 4; ++mt) Bao[mt] = tile_read(smem, mt, l15, kk);
#pragma unroll
    for (int ci = 0; ci < 2; ++ci) {
      int c = (2 * wv + ci) * 16 + l15;
      bf16x8 Aw = *reinterpret_cast<const bf16x8*>(proj_wb + c * DIM_C + kk);
#pragma unroll
      for (int mt = 0; mt < 4; ++mt) acc2[ci][mt] = MFMA16(Aw, Bao[mt], acc2[ci][mt]);
    }
  }
  float* ob = out + (size_t)b * (N_TOK * DIM_C);
#pragma unroll
  for (int ci = 0; ci < 2; ++ci) {
    int c0 = (2 * wv + ci) * 16 + lgp * 4;
    f32x4 pb = *reinterpret_cast<const f32x4*>(proj_b + c0);
#pragma unroll
    for (int mt = 0; mt < 4; ++mt) {
      int mrow = mt * 16 + l15;
      if (mrow < N_TOK) {
        f32x4 o;
#pragma unroll
        for (int r = 0; r < 4; ++r) o[r] = acc2[ci][mt][r] + pb[r];
        *reinterpret_cast<f32x4*>(ob + mrow * 256 + c0) = o;
      }
    }
  }
}

extern "C" void kernel_launch(void* const* d_in, const int* in_sizes, int n_in,
                              void* d_out, int out_size, void* d_ws, size_t ws_size,
                              hipStream_t stream) {
  const float* x          = (const float*)d_in[0];
  const float* mask       = (const float*)d_in[1];
  const float* qkv_w      = (const float*)d_in[2];
  const float* qkv_b      = (const float*)d_in[3];
  const float* proj_w     = (const float*)d_in[4];
  const float* proj_b     = (const float*)d_in[5];
  const float* bias_table = (const float*)d_in[6];
  const int*   rel_index  = (const int*)d_in[7];

  float* cb      = (float*)d_ws;
  bf16*  qkv_wb  = (bf16*)((char*)d_ws + CB_BYTES);
  bf16*  proj_wb = (bf16*)((char*)d_ws + CB_BYTES + QKVW_ELEMS * 2);

  hipLaunchKernelGGL(build_cb_kernel, dim3(8192), dim3(256), 0, stream,
                     bias_table, mask, rel_index, cb);
  hipLaunchKernelGGL(cvt_w_kernel, dim3(1024), dim3(256), 0, stream,
                     qkv_w, proj_w, qkv_wb, proj_wb);
  hipLaunchKernelGGL(win_attn_kernel, dim3(4096), dim3(512), 0, stream,
                     x, qkv_wb, qkv_b, proj_wb, proj_b, cb, (float*)d_out);
}

// Round 7
// 435.397 us; speedup vs baseline: 1.1741x; 1.1741x over previous
//
#include <hip/hip_runtime.h>
#include <hip/hip_bf16.h>

typedef __bf16 bf16;
typedef __bf16 bf16x8 __attribute__((ext_vector_type(8)));
typedef float  f32x4  __attribute__((ext_vector_type(4)));

#define MFMA16(A,B,C) __builtin_amdgcn_mfma_f32_16x16x32_bf16((A),(B),(C),0,0,0)

constexpr float SCALE = 0.17677669529663687f;   // 32^-0.5

// ---- ws layout (bytes) ----
constexpr size_t CB_OFF    = 0;                        // f32 [64 w][8 h][64 m][64 j] = 8 MB
constexpr size_t QKVW_OFF  = 8388608;                  // bf16 [768][256]
constexpr size_t PROJW_OFF = QKVW_OFF + 768*256*2;     // bf16 [256][256]
constexpr size_t QI_OFF    = PROJW_OFF + 256*256*2;    // 8,912,896 (256B aligned)
constexpr size_t TEN_ELEMS = 51380224ull;              // 4096*8*49*32 (bf16 elems)
constexpr size_t AO_OFF    = QI_OFF + 3*TEN_ELEMS*2;   // bf16 [200704][256]

__global__ __launch_bounds__(256) void build_cb_kernel(
    const float* __restrict__ bias_table, const float* __restrict__ mask,
    const int* __restrict__ rel_index, float* __restrict__ cb) {
  int idx = blockIdx.x * 256 + threadIdx.x;            // [64 w][8 h][64 m][64 j]
  int j = idx & 63, m = (idx >> 6) & 63, h = (idx >> 12) & 7, w = idx >> 15;
  float v = 0.f;
  if (j < 49 && m < 49)
    v = bias_table[rel_index[m * 49 + j] * 8 + h] + mask[(w * 49 + m) * 49 + j];
  cb[idx] = v;
}

__global__ __launch_bounds__(256) void cvt_w_kernel(
    const float* __restrict__ qkv_w, const float* __restrict__ proj_w,
    bf16* __restrict__ qkv_wb, bf16* __restrict__ proj_wb) {
  int i = blockIdx.x * 256 + threadIdx.x;              // 262,144 total
  if (i < 768 * 256) qkv_wb[i] = (bf16)qkv_w[i];
  else               proj_wb[i - 768 * 256] = (bf16)proj_w[i - 768 * 256];
}

// swizzled LDS tile helper: [row][64 k], 8-elem chunks XOR'd by row&7
__device__ __forceinline__ bf16x8 frag(const bf16* S, int row, int kchunk) {
  return *reinterpret_cast<const bf16x8*>(&S[row * 64 + ((kchunk ^ (row & 7)) * 8)]);
}

// ---------------------------------------------------------------------------
// GEMM A: qkv = x @ qkv_w^T (+bias, Q pre-scaled), scatter to q/k/v[b][h][m][32]
// tiles: BM=128 BN=128 BK=64; grid 1568*6, XCD-chunked
// ---------------------------------------------------------------------------
__global__ __launch_bounds__(256) void gemm_qkv_kernel(
    const float* __restrict__ x, const bf16* __restrict__ qkv_wb,
    const float* __restrict__ qkv_b, bf16* __restrict__ qkv_i) {
  __shared__ __align__(16) bf16 As[128 * 64];
  __shared__ __align__(16) bf16 Bs[128 * 64];
  const int bid = blockIdx.x;
  const int xcd = bid & 7, idx = bid >> 3;             // 9408 = 8 * 1176
  const int m_t = xcd * 196 + idx / 6;
  const int n_t = idx % 6;
  const int tid = threadIdx.x;
  const int wv = tid >> 6, l = tid & 63, l15 = l & 15, lgp = l >> 4;
  const int wr = wv >> 1, wc = wv & 1;

  const f32x4 fzero = {0.f, 0.f, 0.f, 0.f};
  f32x4 acc[4][4];
#pragma unroll
  for (int mt = 0; mt < 4; ++mt)
#pragma unroll
    for (int nt = 0; nt < 4; ++nt) acc[mt][nt] = fzero;

  for (int ks = 0; ks < 4; ++ks) {
    const int k0 = ks * 64;
    // stage A (f32 -> bf16), 1024 8-elem chunks
#pragma unroll
    for (int i = 0; i < 4; ++i) {
      int c = i * 256 + tid;
      int row = c >> 3, kc = c & 7;
      const float* src = x + (size_t)(m_t * 128 + row) * 256 + k0 + kc * 8;
      f32x4 f0 = *reinterpret_cast<const f32x4*>(src);
      f32x4 f1 = *reinterpret_cast<const f32x4*>(src + 4);
      bf16x8 v8;
#pragma unroll
      for (int e = 0; e < 4; ++e) { v8[e] = (bf16)f0[e]; v8[e + 4] = (bf16)f1[e]; }
      *reinterpret_cast<bf16x8*>(&As[row * 64 + ((kc ^ (row & 7)) * 8)]) = v8;
    }
    // stage B (bf16 weights)
#pragma unroll
    for (int i = 0; i < 4; ++i) {
      int c = i * 256 + tid;
      int row = c >> 3, kc = c & 7;
      bf16x8 w8 = *reinterpret_cast<const bf16x8*>(
          qkv_wb + (size_t)(n_t * 128 + row) * 256 + k0 + kc * 8);
      *reinterpret_cast<bf16x8*>(&Bs[row * 64 + ((kc ^ (row & 7)) * 8)]) = w8;
    }
    __syncthreads();
#pragma unroll
    for (int kk = 0; kk < 2; ++kk) {
      bf16x8 Af[4], Bf[4];
#pragma unroll
      for (int mt = 0; mt < 4; ++mt) Af[mt] = frag(As, wr * 64 + mt * 16 + l15, kk * 4 + lgp);
#pragma unroll
      for (int nt = 0; nt < 4; ++nt) Bf[nt] = frag(Bs, wc * 64 + nt * 16 + l15, kk * 4 + lgp);
#pragma unroll
      for (int mt = 0; mt < 4; ++mt)
#pragma unroll
        for (int nt = 0; nt < 4; ++nt) acc[mt][nt] = MFMA16(Af[mt], Bf[nt], acc[mt][nt]);
    }
    __syncthreads();
  }

  // epilogue: scatter to q/k/v [b][h][49][32] with bias (+SCALE for q)
  const int tsel = n_t >> 1;                           // 0:q 1:k 2:v (uniform)
  bf16* tb = qkv_i + (size_t)tsel * TEN_ELEMS;
  const float sc = (tsel == 0) ? SCALE : 1.0f;
  float bias[4]; int hh[4], dd[4];
#pragma unroll
  for (int nt = 0; nt < 4; ++nt) {
    int n_g = n_t * 128 + wc * 64 + nt * 16 + l15;
    bias[nt] = qkv_b[n_g];
    int nl = n_g & 255;
    hh[nt] = nl >> 5; dd[nt] = nl & 31;
  }
#pragma unroll
  for (int mt = 0; mt < 4; ++mt) {
#pragma unroll
    for (int r = 0; r < 4; ++r) {
      int r_g = m_t * 128 + wr * 64 + mt * 16 + lgp * 4 + r;
      int b = r_g / 49, m = r_g - b * 49;
#pragma unroll
      for (int nt = 0; nt < 4; ++nt) {
        tb[((size_t)(b * 8 + hh[nt]) * 49 + m) * 32 + dd[nt]] =
            (bf16)((acc[mt][nt][r] + bias[nt]) * sc);
      }
    }
  }
}

// ---------------------------------------------------------------------------
// D-frag pair (16x16 tiles Ta=rows 0-15, Tb=rows 16-31 along p) -> A/B frag
// over k=p. Validated R5/R6 audit. Output lane(l15,lgp) reg u: p = lgp*8+u.
// ---------------------------------------------------------------------------
__device__ __forceinline__ bf16x8 repack8(f32x4 Ta, f32x4 Tb, int l15, int lgp) {
  const int s0 = l15 + ((lgp & 1) << 5);
  const bool hi = (lgp & 2) != 0;
  bf16x8 F;
#pragma unroll
  for (int r = 0; r < 4; ++r) {
    float a0 = __shfl(Ta[r], s0);
    float b0 = __shfl(Tb[r], s0);
    F[r] = (bf16)(hi ? b0 : a0);
    float a1 = __shfl(Ta[r], s0 + 16);
    float b1 = __shfl(Tb[r], s0 + 16);
    F[r + 4] = (bf16)(hi ? b1 : a1);
  }
  return F;
}

// ---------------------------------------------------------------------------
// attn: one wave per (window b, head h). S^T = K.Q -> register softmax ->
// PV -> ao[b*49+m][256]. grid 8192 x 256 thr (4 waves).
// ---------------------------------------------------------------------------
__global__ __launch_bounds__(256) void attn_kernel(
    const bf16* __restrict__ qkv_i, const float* __restrict__ cb,
    bf16* __restrict__ ao) {
  __shared__ __align__(16) bf16 Vs[4][64 * 32];
  const int tid = threadIdx.x, wv = tid >> 6, l = tid & 63;
  const int l15 = l & 15, lgp = l >> 4;
  const int g = blockIdx.x * 4 + wv;
  const int b = g >> 3, h = g & 7;

  const bf16* qp = qkv_i + (size_t)(b * 8 + h) * 1568;          // 49*32
  const bf16* kp = qp + TEN_ELEMS;
  const bf16* vp = kp + TEN_ELEMS;
  bf16* vsm = &Vs[wv][0];

  // stage V rows 0..48: 1568 elems = 196 chunks of 8 (FIX: was 4-elem chunks)
#pragma unroll
  for (int i = 0; i < 4; ++i) {
    int c = i * 64 + l;
    if (c < 196)
      *reinterpret_cast<bf16x8*>(&vsm[c * 8]) =
          *reinterpret_cast<const bf16x8*>(vp + c * 8);
  }
  // zero rows 49..63: 480 elems = 60 chunks of 8
  {
    const bf16x8 z8 = {(bf16)0.f,(bf16)0.f,(bf16)0.f,(bf16)0.f,
                       (bf16)0.f,(bf16)0.f,(bf16)0.f,(bf16)0.f};
    if (l < 60) *reinterpret_cast<bf16x8*>(&vsm[1568 + l * 8]) = z8;
  }
  __syncthreads();

  bf16x8 Qf[4], Kf[4];
#pragma unroll
  for (int mt = 0; mt < 4; ++mt) {
    int m = mt * 16 + l15; int mc = m < 49 ? m : 48;
    Qf[mt] = *reinterpret_cast<const bf16x8*>(qp + mc * 32 + lgp * 8);
  }
#pragma unroll
  for (int jt = 0; jt < 4; ++jt) {
    int j = jt * 16 + l15; int jc = j < 49 ? j : 48;
    Kf[jt] = *reinterpret_cast<const bf16x8*>(kp + jc * 32 + lgp * 8);
  }
  // V B-frags: lane l15 = col d, k = j (per-elem LDS gather)
  bf16x8 Vb[2][2];
#pragma unroll
  for (int dt = 0; dt < 2; ++dt)
#pragma unroll
    for (int ksx = 0; ksx < 2; ++ksx) {
#pragma unroll
      for (int u = 0; u < 8; ++u) {
        int j = ksx * 32 + lgp * 8 + u;
        Vb[dt][ksx][u] = vsm[j * 32 + dt * 16 + l15];
      }
    }

  const float* cbp = cb + (size_t)((b & 63) * 8 + h) * 4096;
  bf16* aob = ao + (size_t)b * 12544;                  // 49*256
  const f32x4 fzero = {0.f, 0.f, 0.f, 0.f};

#pragma unroll
  for (int mt = 0; mt < 4; ++mt) {
    int mrow = mt * 16 + l15;
    f32x4 e4[4];
#pragma unroll
    for (int jt = 0; jt < 4; ++jt) e4[jt] = MFMA16(Kf[jt], Qf[mt], fzero);
#pragma unroll
    for (int jt = 0; jt < 4; ++jt) {
      f32x4 c4 = *reinterpret_cast<const f32x4*>(cbp + mrow * 64 + jt * 16 + lgp * 4);
#pragma unroll
      for (int r = 0; r < 4; ++r) e4[jt][r] += c4[r];
    }
    // kill pad keys j>=49 (jt==3: j = 48 + lgp*4 + r, keep only j==48)
    if (lgp != 0) { e4[3][0] = -3.0e38f; }
    e4[3][1] = -3.0e38f; e4[3][2] = -3.0e38f; e4[3][3] = -3.0e38f;

    float mx = e4[0][0];
#pragma unroll
    for (int jt = 0; jt < 4; ++jt)
#pragma unroll
      for (int r = 0; r < 4; ++r) mx = fmaxf(mx, e4[jt][r]);
    mx = fmaxf(mx, __shfl_xor(mx, 16));
    mx = fmaxf(mx, __shfl_xor(mx, 32));
    float sum = 0.f;
#pragma unroll
    for (int jt = 0; jt < 4; ++jt)
#pragma unroll
      for (int r = 0; r < 4; ++r) {
        float ex = __expf(e4[jt][r] - mx);
        e4[jt][r] = ex;
        sum += ex;
      }
    sum += __shfl_xor(sum, 16);
    sum += __shfl_xor(sum, 32);
    float rinv = 1.0f / sum;
#pragma unroll
    for (int jt = 0; jt < 4; ++jt)
#pragma unroll
      for (int r = 0; r < 4; ++r) e4[jt][r] *= rinv;   // normalized P

    bf16x8 Pf0 = repack8(e4[0], e4[1], l15, lgp);      // k = j in [0,32)
    bf16x8 Pf1 = repack8(e4[2], e4[3], l15, lgp);      // k = j in [32,64)
    f32x4 pv[2];
#pragma unroll
    for (int dt = 0; dt < 2; ++dt) {
      pv[dt] = MFMA16(Pf0, Vb[dt][0], fzero);
      pv[dt] = MFMA16(Pf1, Vb[dt][1], pv[dt]);
    }
    // D: col l15 = d, row = m = mt*16 + lgp*4 + r
#pragma unroll
    for (int r = 0; r < 4; ++r) {
      int m_g = mt * 16 + lgp * 4 + r;
      if (m_g < 49) {
#pragma unroll
        for (int dt = 0; dt < 2; ++dt)
          aob[m_g * 256 + h * 32 + dt * 16 + l15] = (bf16)pv[dt][r];
      }
    }
  }
}

// ---------------------------------------------------------------------------
// GEMM C: out = ao @ proj_w^T + proj_b  (dense f32 output)
// ---------------------------------------------------------------------------
__global__ __launch_bounds__(256) void gemm_proj_kernel(
    const bf16* __restrict__ ao, const bf16* __restrict__ proj_wb,
    const float* __restrict__ proj_b, float* __restrict__ out) {
  __shared__ __align__(16) bf16 As[128 * 64];
  __shared__ __align__(16) bf16 Bs[128 * 64];
  const int bid = blockIdx.x;                          // 3136 = 8 * 392
  const int xcd = bid & 7, idx = bid >> 3;
  const int m_t = xcd * 196 + idx / 2;
  const int n_t = idx % 2;
  const int tid = threadIdx.x;
  const int wv = tid >> 6, l = tid & 63, l15 = l & 15, lgp = l >> 4;
  const int wr = wv >> 1, wc = wv & 1;

  const f32x4 fzero = {0.f, 0.f, 0.f, 0.f};
  f32x4 acc[4][4];
#pragma unroll
  for (int mt = 0; mt < 4; ++mt)
#pragma unroll
    for (int nt = 0; nt < 4; ++nt) acc[mt][nt] = fzero;

  for (int ks = 0; ks < 4; ++ks) {
    const int k0 = ks * 64;
#pragma unroll
    for (int i = 0; i < 4; ++i) {
      int c = i * 256 + tid;
      int row = c >> 3, kc = c & 7;
      bf16x8 a8 = *reinterpret_cast<const bf16x8*>(
          ao + (size_t)(m_t * 128 + row) * 256 + k0 + kc * 8);
      *reinterpret_cast<bf16x8*>(&As[row * 64 + ((kc ^ (row & 7)) * 8)]) = a8;
      bf16x8 w8 = *reinterpret_cast<const bf16x8*>(
          proj_wb + (size_t)(n_t * 128 + row) * 256 + k0 + kc * 8);
      *reinterpret_cast<bf16x8*>(&Bs[row * 64 + ((kc ^ (row & 7)) * 8)]) = w8;
    }
    __syncthreads();
#pragma unroll
    for (int kk = 0; kk < 2; ++kk) {
      bf16x8 Af[4], Bf[4];
#pragma unroll
      for (int mt = 0; mt < 4; ++mt) Af[mt] = frag(As, wr * 64 + mt * 16 + l15, kk * 4 + lgp);
#pragma unroll
      for (int nt = 0; nt < 4; ++nt) Bf[nt] = frag(Bs, wc * 64 + nt * 16 + l15, kk * 4 + lgp);
#pragma unroll
      for (int mt = 0; mt < 4; ++mt)
#pragma unroll
        for (int nt = 0; nt < 4; ++nt) acc[mt][nt] = MFMA16(Af[mt], Bf[nt], acc[mt][nt]);
    }
    __syncthreads();
  }

  float bias[4]; int cg[4];
#pragma unroll
  for (int nt = 0; nt < 4; ++nt) {
    cg[nt] = n_t * 128 + wc * 64 + nt * 16 + l15;
    bias[nt] = proj_b[cg[nt]];
  }
#pragma unroll
  for (int mt = 0; mt < 4; ++mt) {
#pragma unroll
    for (int r = 0; r < 4; ++r) {
      size_t r_g = (size_t)(m_t * 128 + wr * 64 + mt * 16 + lgp * 4 + r);
#pragma unroll
      for (int nt = 0; nt < 4; ++nt)
        out[r_g * 256 + cg[nt]] = acc[mt][nt][r] + bias[nt];
    }
  }
}

extern "C" void kernel_launch(void* const* d_in, const int* in_sizes, int n_in,
                              void* d_out, int out_size, void* d_ws, size_t ws_size,
                              hipStream_t stream) {
  const float* x          = (const float*)d_in[0];
  const float* mask       = (const float*)d_in[1];
  const float* qkv_w      = (const float*)d_in[2];
  const float* qkv_b      = (const float*)d_in[3];
  const float* proj_w     = (const float*)d_in[4];
  const float* proj_b     = (const float*)d_in[5];
  const float* bias_table = (const float*)d_in[6];
  const int*   rel_index  = (const int*)d_in[7];

  char* ws = (char*)d_ws;
  float* cb      = (float*)(ws + CB_OFF);
  bf16*  qkv_wb  = (bf16*)(ws + QKVW_OFF);
  bf16*  proj_wb = (bf16*)(ws + PROJW_OFF);
  bf16*  qkv_i   = (bf16*)(ws + QI_OFF);     // q,k,v each TEN_ELEMS
  bf16*  ao      = (bf16*)(ws + AO_OFF);     // [200704][256]

  hipLaunchKernelGGL(build_cb_kernel, dim3(8192), dim3(256), 0, stream,
                     bias_table, mask, rel_index, cb);
  hipLaunchKernelGGL(cvt_w_kernel, dim3(1024), dim3(256), 0, stream,
                     qkv_w, proj_w, qkv_wb, proj_wb);
  hipLaunchKernelGGL(gemm_qkv_kernel, dim3(9408), dim3(256), 0, stream,
                     x, qkv_wb, qkv_b, qkv_i);
  hipLaunchKernelGGL(attn_kernel, dim3(8192), dim3(256), 0, stream,
                     qkv_i, cb, ao);
  hipLaunchKernelGGL(gemm_proj_kernel, dim3(3136), dim3(256), 0, stream,
                     ao, proj_wb, proj_b, (float*)d_out);
}